// Round 2
// baseline (1558.698 us; speedup 1.0000x reference)
//
#include <hip/hip_runtime.h>
#include <hip/hip_bf16.h>

// ---------------------------------------------------------------------------
// PointPillars encoder, fp32 reference-exact path.
// Stages: repack conv weights -> h2(0) vector -> point MLP + atomicMax scatter
//         -> per-cell zero-slot finish -> 4x direct conv3x3 (NHWC, LDS tile).
// ---------------------------------------------------------------------------

#define NXG 256
#define NYG 256

__global__ __launch_bounds__(256) void repack_w(const float* __restrict__ src,
                                                float* __restrict__ dst,
                                                int Cin, int Cout) {
    // src OIHW [co][ci][ky][kx] -> dst [t][ci][co], t = ky*3+kx
    int i = blockIdx.x * 256 + threadIdx.x;
    int total = Cout * Cin * 9;
    if (i >= total) return;
    int co = i / (Cin * 9);
    int r  = i - co * (Cin * 9);
    int ci = r / 9;
    int t  = r - ci * 9;
    dst[(t * Cin + ci) * Cout + co] = src[i];
}

__global__ void h2zero_k(const float* __restrict__ t1, const float* __restrict__ w2,
                         const float* __restrict__ s2, const float* __restrict__ t2,
                         float* __restrict__ h2z) {
    int co = threadIdx.x;  // 64 threads
    float acc = 0.f;
    for (int j = 0; j < 32; j++) {
        float h1 = fmaxf(t1[j], 0.f);
        acc += h1 * w2[j * 64 + co];
    }
    h2z[co] = fmaxf(acc * s2[co] + t2[co], 0.f);
}

__global__ __launch_bounds__(256) void point_mlp(
    const float4* __restrict__ pts, int n,
    const float* __restrict__ w1, const float* __restrict__ s1, const float* __restrict__ t1,
    const float* __restrict__ w2, const float* __restrict__ s2, const float* __restrict__ t2,
    int* __restrict__ cnt, float* __restrict__ desc) {
    int i = blockIdx.x * 256 + threadIdx.x;
    if (i >= n) return;
    float4 p = pts[i];
    float x = p.x, y = p.y, z = p.z, inten = p.w;
    if (!(x >= -51.2f && x < 51.2f && y >= -51.2f && y < 51.2f)) return;
    // IEEE division to match reference floor((x - X_MIN)/X_RES) exactly.
    float qx = (x - (-51.2f)) / 0.4f;
    float qy = (y - (-51.2f)) / 0.4f;
    int xi = (int)floorf(qx); xi = xi < 0 ? 0 : (xi > 255 ? 255 : xi);
    int yi = (int)floorf(qy); yi = yi < 0 ? 0 : (yi > 255 ? 255 : yi);
    int cell = yi * NXG + xi;
    int slot = atomicAdd(&cnt[cell], 1);
    if (slot >= 32) return;  // statistically never hit at lambda~2.6
    float cx = (float)xi * 0.4f + -51.0f;
    float cy = (float)yi * 0.4f + -51.0f;
    float f0 = x, f1 = y, f2 = z, f3 = inten, f4 = x - cx, f5 = y - cy, f6 = z;
    float h1[32];
#pragma unroll
    for (int k = 0; k < 32; k++) {
        float a = f0 * w1[0 * 32 + k] + f1 * w1[1 * 32 + k] + f2 * w1[2 * 32 + k]
                + f3 * w1[3 * 32 + k] + f4 * w1[4 * 32 + k] + f5 * w1[5 * 32 + k]
                + f6 * w1[6 * 32 + k];
        h1[k] = fmaxf(a * s1[k] + t1[k], 0.f);
    }
    unsigned int* dc = (unsigned int*)(desc + (size_t)cell * 64);
#pragma unroll 4
    for (int co = 0; co < 64; co++) {
        float a = 0.f;
#pragma unroll
        for (int j = 0; j < 32; j++) a += h1[j] * w2[j * 64 + co];
        float v = fmaxf(a * s2[co] + t2[co], 0.f);
        // all values >= 0 -> uint compare == float compare; desc pre-zeroed.
        atomicMax(&dc[co], __float_as_uint(v));
    }
}

__global__ __launch_bounds__(256) void cell_finish(const int* __restrict__ cnt,
                                                   const float* __restrict__ h2z,
                                                   float* __restrict__ desc) {
    int i = blockIdx.x * 256 + threadIdx.x;  // over 65536*64
    int cell = i >> 6;
    int co = i & 63;
    int c = cnt[cell];
    if (c > 0 && c < 32) {
        float zv = h2z[co];
        float v = desc[i];
        desc[i] = fmaxf(v, zv);
    }
}

// Direct 3x3 conv, NHWC activations. Block = 16x16 pixel tile, 32 couts.
// Input tile (18x18 x 32cin-chunk) staged in LDS; weights [t][ci][co] read
// wave-uniformly (scalar loads). Thread = 1 pixel, 32 fp32 accumulators.
template <int CIN, int COUT, bool NCHW_OUT>
__global__ __launch_bounds__(256) void conv3x3(const float* __restrict__ in,
                                               const float* __restrict__ wT,
                                               const float* __restrict__ bs,
                                               const float* __restrict__ bt,
                                               float* __restrict__ out) {
    __shared__ float lds[18 * 18 * 32];  // 41,472 B
    const int tid = threadIdx.x;
    const int bx = blockIdx.x, by = blockIdx.y;
    const int coBase = blockIdx.z * 32;
    const int px = tid & 15, py = tid >> 4;

    float acc[32];
#pragma unroll
    for (int k = 0; k < 32; k++) acc[k] = 0.f;

    for (int cc = 0; cc < CIN / 32; ++cc) {
        if (cc) __syncthreads();
        // stage 18x18 halo tile for this 32-cin chunk
        for (int i = tid; i < 18 * 18 * 8; i += 256) {
            int p = i >> 3, c4 = i & 7;
            int ty = p / 18, tx = p - ty * 18;
            int gy = by * 16 + ty - 1, gx = bx * 16 + tx - 1;
            float4 v = make_float4(0.f, 0.f, 0.f, 0.f);
            if (gy >= 0 && gy < NYG && gx >= 0 && gx < NXG)
                v = *(const float4*)&in[((size_t)(gy * NXG + gx)) * CIN + cc * 32 + c4 * 4];
            *(float4*)&lds[p * 32 + c4 * 4] = v;
        }
        __syncthreads();

#pragma unroll 1
        for (int t = 0; t < 9; ++t) {
            int ky = t / 3, kx = t - ky * 3;
            int base = ((py + ky) * 18 + (px + kx)) * 32;
            const float* w = wT + ((size_t)(t * CIN + cc * 32)) * COUT + coBase;
#pragma unroll
            for (int c4 = 0; c4 < 8; c4++) {
                float4 xv = *(const float4*)&lds[base + c4 * 4];
#pragma unroll
                for (int j = 0; j < 4; j++) {
                    float xs = (j == 0) ? xv.x : (j == 1) ? xv.y : (j == 2) ? xv.z : xv.w;
                    const float* wr = w + (size_t)(c4 * 4 + j) * COUT;
#pragma unroll
                    for (int co = 0; co < 32; co += 4) {
                        float4 wv = *(const float4*)&wr[co];
                        acc[co + 0] += xs * wv.x;
                        acc[co + 1] += xs * wv.y;
                        acc[co + 2] += xs * wv.z;
                        acc[co + 3] += xs * wv.w;
                    }
                }
            }
        }
    }

    int gy = by * 16 + py, gx = bx * 16 + px;
#pragma unroll
    for (int co = 0; co < 32; co++) {
        float v = fmaxf(acc[co] * bs[coBase + co] + bt[coBase + co], 0.f);
        if (NCHW_OUT)
            out[(size_t)(coBase + co) * (NXG * NYG) + gy * NXG + gx] = v;
        else
            out[((size_t)(gy * NXG + gx)) * COUT + coBase + co] = v;
    }
}

extern "C" void kernel_launch(void* const* d_in, const int* in_sizes, int n_in,
                              void* d_out, int out_size, void* d_ws, size_t ws_size,
                              hipStream_t stream) {
    const float* points = (const float*)d_in[0];
    const float* w1 = (const float*)d_in[1];
    const float* s1 = (const float*)d_in[2];
    const float* t1 = (const float*)d_in[3];
    const float* w2 = (const float*)d_in[4];
    const float* s2 = (const float*)d_in[5];
    const float* t2 = (const float*)d_in[6];
    const float* cw1a = (const float*)d_in[7];
    const float* cs1a = (const float*)d_in[8];
    const float* ct1a = (const float*)d_in[9];
    const float* cw1b = (const float*)d_in[10];
    const float* cs1b = (const float*)d_in[11];
    const float* ct1b = (const float*)d_in[12];
    const float* cw2a = (const float*)d_in[13];
    const float* cs2a = (const float*)d_in[14];
    const float* ct2a = (const float*)d_in[15];
    const float* cw2b = (const float*)d_in[16];
    const float* cs2b = (const float*)d_in[17];
    const float* ct2b = (const float*)d_in[18];
    int n = in_sizes[0] / 4;

    // Workspace layout (compacted, ~82 MB total):
    //   [0,       256K)  cnt
    //   [256K,    ~1.6M) repacked weights + h2z
    //   [2M,      18M)   R0: desc / conv input, 64ch NHWC (16 MB)
    //   [18M,     50M)   R1: 128ch NHWC (32 MB)
    //   [50M,     82M)   R2: 128ch NHWC (32 MB)
    char* ws = (char*)d_ws;
    int*   cnt  = (int*)ws;                      // 256 KB
    float* wT1a = (float*)(ws + 262144);         // 288 KB
    float* wT1b = (float*)(ws + 557056);         // 576 KB
    float* wT2a = (float*)(ws + 1146880);        // 288 KB
    float* wT2b = (float*)(ws + 1441792);        // 144 KB
    float* h2z  = (float*)(ws + 1589248);        // 256 B
    float* R0 = (float*)(ws + (2ull << 20));
    float* R1 = (float*)(ws + (2ull << 20) + (16ull << 20));
    float* R2 = (float*)(ws + (2ull << 20) + (48ull << 20));

    hipMemsetAsync(cnt, 0, 262144, stream);
    hipMemsetAsync(R0, 0, 64ull * 65536ull * 4ull, stream);  // desc zero-init

    repack_w<<<(128 * 64 * 9 + 255) / 256, 256, 0, stream>>>(cw1a, wT1a, 64, 128);
    repack_w<<<(128 * 128 * 9 + 255) / 256, 256, 0, stream>>>(cw1b, wT1b, 128, 128);
    repack_w<<<(64 * 128 * 9 + 255) / 256, 256, 0, stream>>>(cw2a, wT2a, 128, 64);
    repack_w<<<(64 * 64 * 9 + 255) / 256, 256, 0, stream>>>(cw2b, wT2b, 64, 64);
    h2zero_k<<<1, 64, 0, stream>>>(t1, w2, s2, t2, h2z);

    point_mlp<<<(n + 255) / 256, 256, 0, stream>>>((const float4*)points, n,
                                                   w1, s1, t1, w2, s2, t2, cnt, R0);
    cell_finish<<<65536 * 64 / 256, 256, 0, stream>>>(cnt, h2z, R0);

    conv3x3<64, 128, false><<<dim3(16, 16, 4), 256, 0, stream>>>(R0, wT1a, cs1a, ct1a, R1);
    conv3x3<128, 128, false><<<dim3(16, 16, 4), 256, 0, stream>>>(R1, wT1b, cs1b, ct1b, R2);
    conv3x3<128, 64, false><<<dim3(16, 16, 2), 256, 0, stream>>>(R2, wT2a, cs2a, ct2a, R0);
    conv3x3<64, 64, true><<<dim3(16, 16, 2), 256, 0, stream>>>(R0, wT2b, cs2b, ct2b, (float*)d_out);
}